// Round 5
// baseline (1114.879 us; speedup 1.0000x reference)
//
#include <hip/hip_runtime.h>
#include <hip/hip_bf16.h>

// Deep Hough transform — region-partial gather.
// Sizes fixed by setup_inputs(): N=8, C=128, H=W=128, A=R=120.
#define NC    1024
#define HW    16384
#define HH    128
#define WW    128
#define NA    120
#define NR    120
#define G     8            // row-slabs of 16 rows = 8 MB of featT each; slab g -> XCD g
#define NB2   (G * NR)     // 960 counting-sort bins per angle: key = g*NR + r
#define PI_D  3.14159265358979323846

typedef float vfloat4 __attribute__((ext_vector_type(4)));   // native vec for nontemporal

// ---------------- main-path workspace layout (bytes) ----------------
#define WS_FEATT 0UL            // 67,108,864  (reused as outT after k_gather2)
#define WS_PLIST 67108864UL     //  3,932,160  u16 pixel ids, sorted by (g,r) per angle
#define WS_OFFS2 71041024UL     //    461,284  CSR: 120 x (960+1) int
#define WS_CNTS2 71503872UL     //    460,800
#define WS_TABS  71964672UL     //        960
#define WS_RB    71965696UL     //      3,840  rb[a][g]   = first non-empty r of band
#define WS_BASE  71969792UL     //      3,840  base[a][g] = slot prefix
#define WS_PART  72351744UL     // partial sums, 4 KB per (a,g,r) band slot
#define PART_CAP 80000UL        // slots; analytic need ~59K (sum over a,g of band width)
#define WS_NEEDED (WS_PART + PART_CAP * 4096UL)   // ~400 MB

// ---------------- fallback (round-3) workspace layout ----------------
#define F_FEATT 0UL
#define F_OUTT  67108864UL
#define F_PLIST (67108864UL + 58982400UL)
#define F_TABS  (126091264UL + 3932160UL)
#define F_CNTS  (130023424UL + 1024UL)
#define F_OFFS  (130024448UL + 57600UL + 64UL)

// ---- cos/sin tables, fp64 exactly like numpy then cast to f32 ----
__global__ void k_tab(float* __restrict__ tabs) {
    int a = threadIdx.x;
    if (a < NA) {
        double itheta = PI_D / (double)NA;
        double diag   = sqrt((double)(HH * HH + WW * WW));
        double irho   = floor(diag + 1.0) / (double)(NR - 1);   // 182/119
        double ang    = (double)a * itheta;
        tabs[a]       = (float)(cos(ang) / irho);
        tabs[NA + a]  = (float)(sin(ang) / irho);
    }
}

// rho bin — MUST match numpy: f32 mul, f32 mul, f32 add (no fma), rint, clip.
__device__ __forceinline__ int rho_bin(int p, float tc, float ts) {
#pragma clang fp contract(off)
    int y = p >> 7, x = p & (WW - 1);
    float u = (float)(x - WW / 2) * tc;
    float v = (float)(y - HH / 2) * ts;
    float s = u + v;
    int r = (int)rintf(s) + NR / 2;
    return min(NR - 1, max(0, r));
}

// slab id of pixel p: g = y >> 4 = p >> 11
__device__ __forceinline__ int key2(int p, float tc, float ts) {
    return (p >> 11) * NR + rho_bin(p, tc, ts);
}

// ---- shared register-accumulate over one CSR segment (8-deep MLP) ----
__device__ __forceinline__ float4 accum_bin(const float4* __restrict__ f4,
                                            const unsigned short* __restrict__ pl,
                                            int k0, int k1, int t) {
    float4 a0 = {0.f, 0.f, 0.f, 0.f}, a1 = a0, a2 = a0, a3 = a0;
    int k = k0;
    for (; k + 8 <= k1; k += 8) {
        int p0 = pl[k + 0], p1 = pl[k + 1], p2 = pl[k + 2], p3 = pl[k + 3];
        int p4 = pl[k + 4], p5 = pl[k + 5], p6 = pl[k + 6], p7 = pl[k + 7];
        float4 v0 = f4[(size_t)p0 * 256 + t];
        float4 v1 = f4[(size_t)p1 * 256 + t];
        float4 v2 = f4[(size_t)p2 * 256 + t];
        float4 v3 = f4[(size_t)p3 * 256 + t];
        float4 v4 = f4[(size_t)p4 * 256 + t];
        float4 v5 = f4[(size_t)p5 * 256 + t];
        float4 v6 = f4[(size_t)p6 * 256 + t];
        float4 v7 = f4[(size_t)p7 * 256 + t];
        a0.x += v0.x; a0.y += v0.y; a0.z += v0.z; a0.w += v0.w;
        a1.x += v1.x; a1.y += v1.y; a1.z += v1.z; a1.w += v1.w;
        a2.x += v2.x; a2.y += v2.y; a2.z += v2.z; a2.w += v2.w;
        a3.x += v3.x; a3.y += v3.y; a3.z += v3.z; a3.w += v3.w;
        a0.x += v4.x; a0.y += v4.y; a0.z += v4.z; a0.w += v4.w;
        a1.x += v5.x; a1.y += v5.y; a1.z += v5.z; a1.w += v5.w;
        a2.x += v6.x; a2.y += v6.y; a2.z += v6.z; a2.w += v6.w;
        a3.x += v7.x; a3.y += v7.y; a3.z += v7.z; a3.w += v7.w;
    }
    for (; k + 4 <= k1; k += 4) {
        int p0 = pl[k + 0], p1 = pl[k + 1], p2 = pl[k + 2], p3 = pl[k + 3];
        float4 v0 = f4[(size_t)p0 * 256 + t];
        float4 v1 = f4[(size_t)p1 * 256 + t];
        float4 v2 = f4[(size_t)p2 * 256 + t];
        float4 v3 = f4[(size_t)p3 * 256 + t];
        a0.x += v0.x; a0.y += v0.y; a0.z += v0.z; a0.w += v0.w;
        a1.x += v1.x; a1.y += v1.y; a1.z += v1.z; a1.w += v1.w;
        a2.x += v2.x; a2.y += v2.y; a2.z += v2.z; a2.w += v2.w;
        a3.x += v3.x; a3.y += v3.y; a3.z += v3.z; a3.w += v3.w;
    }
    for (; k < k1; ++k) {
        float4 v = f4[(size_t)pl[k] * 256 + t];
        a0.x += v.x; a0.y += v.y; a0.z += v.z; a0.w += v.w;
    }
    float4 s;
    s.x = (a0.x + a1.x) + (a2.x + a3.x);
    s.y = (a0.y + a1.y) + (a2.y + a3.y);
    s.z = (a0.z + a1.z) + (a2.z + a3.z);
    s.w = (a0.w + a1.w) + (a2.w + a3.w);
    return s;
}

// =================== main path: (g,r) sort + region partials ===================

__global__ __launch_bounds__(256) void k_count2(const float* __restrict__ tabs,
                                                int* __restrict__ cnts2) {
    __shared__ int cnt[NB2];
    int a = blockIdx.x, t = threadIdx.x;
    for (int i = t; i < NB2; i += 256) cnt[i] = 0;
    __syncthreads();
    float tc = tabs[a], ts = tabs[NA + a];
    for (int p = t; p < HW; p += 256)
        atomicAdd(&cnt[key2(p, tc, ts)], 1);
    __syncthreads();
    for (int i = t; i < NB2; i += 256) cnts2[a * NB2 + i] = cnt[i];
}

__global__ void k_scan2(const int* __restrict__ cnts2, int* __restrict__ offs2) {
    int a = threadIdx.x;
    if (a < NA) {
        int base = 0;
        for (int b = 0; b < NB2; ++b) {
            offs2[a * (NB2 + 1) + b] = base;
            base += cnts2[a * NB2 + b];
        }
        offs2[a * (NB2 + 1) + NB2] = base;   // == HW
    }
}

__global__ __launch_bounds__(256) void k_scatter2(const float* __restrict__ tabs,
                                                  const int* __restrict__ offs2,
                                                  unsigned short* __restrict__ plist) {
    __shared__ int cur[NB2];
    int a = blockIdx.x, t = threadIdx.x;
    for (int i = t; i < NB2; i += 256) cur[i] = offs2[a * (NB2 + 1) + i];
    __syncthreads();
    float tc = tabs[a], ts = tabs[NA + a];
    for (int p = t; p < HW; p += 256) {
        int pos = atomicAdd(&cur[key2(p, tc, ts)], 1);
        plist[(size_t)a * HW + pos] = (unsigned short)p;
    }
}

// Per (a,g): band = contiguous non-empty r range [rb, rb+w); compact slot bases.
__global__ void k_meta(const int* __restrict__ offs2, int* __restrict__ rb,
                       int* __restrict__ basep) {
    __shared__ int aw[NA], ab[NA];
    int t = threadIdx.x;
    int w[G], rmn[G];
    if (t < NA) {
        int tot = 0;
#pragma unroll
        for (int g = 0; g < G; ++g) {
            const int* po = offs2 + t * (NB2 + 1) + g * NR;
            int rmin = NR, rmax = -1;
            for (int r = 0; r < NR; ++r)
                if (po[r + 1] > po[r]) { if (r < rmin) rmin = r; rmax = r; }
            rmn[g] = rmin;
            w[g]   = rmax - rmin + 1;    // every slab non-empty at every angle
            tot += w[g];
        }
        aw[t] = tot;
#pragma unroll
        for (int g = 0; g < G; ++g) rb[t * G + g] = rmn[g];
    }
    __syncthreads();
    if (t == 0) {
        int run = 0;
        for (int i = 0; i < NA; ++i) { ab[i] = run; run += aw[i]; }
    }
    __syncthreads();
    if (t < NA) {
        int b = ab[t];
#pragma unroll
        for (int g = 0; g < G; ++g) { basep[t * G + g] = b; b += w[g]; }
    }
}

// transpose feat (NC x HW) -> featT (HW x NC)
__global__ __launch_bounds__(256) void k_tr_in(const float* __restrict__ in,
                                               float* __restrict__ outp) {
    __shared__ float tile[32][33];
    int p0 = blockIdx.x * 32, c0 = blockIdx.y * 32;
    int tx = threadIdx.x, ty = threadIdx.y;
    for (int i = 0; i < 32; i += 8)
        tile[ty + i][tx] = in[(size_t)(c0 + ty + i) * HW + p0 + tx];
    __syncthreads();
    for (int i = 0; i < 32; i += 8)
        outp[(size_t)(p0 + ty + i) * NC + c0 + tx] = tile[tx][ty + i];
}

// Main gather: block = (slab g, angle a, r-parity s). Linear block id
// = g + 8*(a + 120*s) -> XCD = id%8 = g: every block on XCD g reads ONLY
// slab g's 8 MB of featT -> L2-resident across all 120 angles.
__global__ __launch_bounds__(256) void k_gather2(const float4* __restrict__ featT4,
        const int* __restrict__ offs2, const unsigned short* __restrict__ plist,
        const int* __restrict__ rb, const int* __restrict__ basep,
        vfloat4* __restrict__ part4) {
    const int g = blockIdx.x, a = blockIdx.y, s = blockIdx.z;
    const int t = threadIdx.x;
    const unsigned short* pl = plist + (size_t)a * HW;
    const int* po = offs2 + a * (NB2 + 1) + g * NR;
    const long mb = (long)basep[a * G + g] - rb[a * G + g];   // slot = mb + r
    for (int r = s; r < NR; r += 2) {
        int k0 = po[r], k1 = po[r + 1];
        if (k0 == k1) continue;
        float4 v = accum_bin(featT4, pl, k0, k1, t);
        vfloat4 w = {v.x, v.y, v.z, v.w};
        __builtin_nontemporal_store(w, &part4[(size_t)(mb + r) * 256 + t]);
    }
}

// Sum <=8 slab partials per (a,r); emptiness re-derived from offs2 (exact
// same condition the writer used). Writes outT (over the dead featT buffer).
__global__ __launch_bounds__(256) void k_reduce(const float4* __restrict__ part4,
        const int* __restrict__ offs2, const int* __restrict__ rb,
        const int* __restrict__ basep, float4* __restrict__ outT4) {
    const int r = blockIdx.x, a = blockIdx.y, t = threadIdx.x;
    float4 s = {0.f, 0.f, 0.f, 0.f};
#pragma unroll
    for (int g = 0; g < G; ++g) {
        int b = a * (NB2 + 1) + g * NR + r;
        if (offs2[b + 1] > offs2[b]) {
            float4 v = part4[(size_t)(basep[a * G + g] + r - rb[a * G + g]) * 256 + t];
            s.x += v.x; s.y += v.y; s.z += v.z; s.w += v.w;
        }
    }
    outT4[(size_t)(a * NR + r) * 256 + t] = s;
}

// transpose outT ((NA*NR) x NC) -> out (NC x (NA*NR))
__global__ __launch_bounds__(256) void k_tr_out(const float* __restrict__ in,
                                                float* __restrict__ outp) {
    __shared__ float tile[32][33];
    int j0 = blockIdx.x * 32, c0 = blockIdx.y * 32;
    int tx = threadIdx.x, ty = threadIdx.y;
    for (int i = 0; i < 32; i += 8)
        tile[ty + i][tx] = in[(size_t)(j0 + ty + i) * NC + c0 + tx];
    __syncthreads();
    for (int i = 0; i < 32; i += 8)
        outp[(size_t)(c0 + ty + i) * (NA * NR) + j0 + tx] = tile[tx][ty + i];
}

// =================== fallback path (round-3, known-good) ===================

__global__ __launch_bounds__(256) void k_count(const float* __restrict__ tabs,
                                               int* __restrict__ cnts) {
    __shared__ int cnt[NR];
    int a = blockIdx.x, t = threadIdx.x;
    if (t < NR) cnt[t] = 0;
    __syncthreads();
    float tc = tabs[a], ts = tabs[NA + a];
    for (int p = t; p < HW; p += 256)
        atomicAdd(&cnt[rho_bin(p, tc, ts)], 1);
    __syncthreads();
    if (t < NR) cnts[a * NR + t] = cnt[t];
}

__global__ void k_scan(const int* __restrict__ cnts, int* __restrict__ offs) {
    int a = threadIdx.x;
    if (a < NA) {
        int base = 0;
        for (int r = 0; r < NR; ++r) {
            offs[a * (NR + 1) + r] = base;
            base += cnts[a * NR + r];
        }
        offs[a * (NR + 1) + NR] = base;
    }
}

__global__ __launch_bounds__(256) void k_scatter(const float* __restrict__ tabs,
                                                 const int* __restrict__ offs,
                                                 unsigned short* __restrict__ plist) {
    __shared__ int cur[NR];
    int a = blockIdx.x, t = threadIdx.x;
    if (t < NR) cur[t] = offs[a * (NR + 1) + t];
    __syncthreads();
    float tc = tabs[a], ts = tabs[NA + a];
    for (int p = t; p < HW; p += 256) {
        int r = rho_bin(p, tc, ts);
        int pos = atomicAdd(&cur[r], 1);
        plist[(size_t)a * HW + pos] = (unsigned short)p;
    }
}

__global__ __launch_bounds__(256) void k_gather(const float4* __restrict__ featT4,
                                                const int* __restrict__ offs,
                                                const unsigned short* __restrict__ plist,
                                                float4* __restrict__ outT4) {
    const int r = blockIdx.x, a = blockIdx.y, t = threadIdx.x;
    const unsigned short* pl = plist + (size_t)a * HW;
    int k0 = offs[a * (NR + 1) + r];
    int k1 = offs[a * (NR + 1) + r + 1];
    float4 s = accum_bin(featT4, pl, k0, k1, t);
    outT4[(size_t)(a * NR + r) * 256 + t] = s;
}

// =================== launch ===================

extern "C" void kernel_launch(void* const* d_in, const int* in_sizes, int n_in,
                              void* d_out, int out_size, void* d_ws, size_t ws_size,
                              hipStream_t stream) {
    (void)in_sizes; (void)n_in; (void)out_size;
    const float* feat = (const float*)d_in[0];
    float* out = (float*)d_out;
    char* ws = (char*)d_ws;

    if (ws_size >= WS_NEEDED) {
        // ---------------- main path ----------------
        float*          featT = (float*)(ws + WS_FEATT);
        float*          outT  = (float*)(ws + WS_FEATT);   // reuse after gather2
        unsigned short* plist = (unsigned short*)(ws + WS_PLIST);
        int*            offs2 = (int*)(ws + WS_OFFS2);
        int*            cnts2 = (int*)(ws + WS_CNTS2);
        float*          tabs  = (float*)(ws + WS_TABS);
        int*            rb    = (int*)(ws + WS_RB);
        int*            basep = (int*)(ws + WS_BASE);
        float*          part  = (float*)(ws + WS_PART);

        k_tab     <<<1, 128, 0, stream>>>(tabs);
        k_count2  <<<NA, 256, 0, stream>>>(tabs, cnts2);
        k_scan2   <<<1, 128, 0, stream>>>(cnts2, offs2);
        k_scatter2<<<NA, 256, 0, stream>>>(tabs, offs2, plist);
        k_meta    <<<1, 128, 0, stream>>>(offs2, rb, basep);
        k_tr_in   <<<dim3(HW / 32, NC / 32), dim3(32, 8), 0, stream>>>(feat, featT);
        k_gather2 <<<dim3(G, NA, 2), 256, 0, stream>>>(
            (const float4*)featT, offs2, plist, rb, basep, (vfloat4*)part);
        k_reduce  <<<dim3(NR, NA), 256, 0, stream>>>(
            (const float4*)part, offs2, rb, basep, (float4*)outT);
        k_tr_out  <<<dim3((NA * NR) / 32, NC / 32), dim3(32, 8), 0, stream>>>(outT, out);
    } else {
        // ---------------- fallback: round-3 path ----------------
        float*          featT = (float*)(ws + F_FEATT);
        float*          outT  = (float*)(ws + F_OUTT);
        unsigned short* plist = (unsigned short*)(ws + F_PLIST);
        float*          tabs  = (float*)(ws + F_TABS);
        int*            cnts  = (int*)(ws + F_CNTS);
        int*            offs  = (int*)(ws + F_OFFS);

        k_tab    <<<1, 128, 0, stream>>>(tabs);
        k_count  <<<NA, 256, 0, stream>>>(tabs, cnts);
        k_scan   <<<1, 128, 0, stream>>>(cnts, offs);
        k_scatter<<<NA, 256, 0, stream>>>(tabs, offs, plist);
        k_tr_in  <<<dim3(HW / 32, NC / 32), dim3(32, 8), 0, stream>>>(feat, featT);
        k_gather <<<dim3(NR, NA), 256, 0, stream>>>(
            (const float4*)featT, offs, plist, (float4*)outT);
        k_tr_out <<<dim3((NA * NR) / 32, NC / 32), dim3(32, 8), 0, stream>>>(outT, out);
    }
}

// Round 6
// 1077.467 us; speedup vs baseline: 1.0347x; 1.0347x over previous
//
#include <hip/hip_runtime.h>
#include <hip/hip_bf16.h>

// Deep Hough transform — slab x channel-half gather, atomic merge.
// Sizes fixed by setup_inputs(): N=8, C=128, H=W=128, A=R=120.
#define NC    1024
#define HW    16384
#define HH    128
#define WW    128
#define NA    120
#define NR    120
#define G     8            // row-slabs of 16 rows; slab g -> XCD g
#define NB2   (G * NR)     // 960 counting-sort bins per angle: key = g*NR + r
#define PI_D  3.14159265358979323846

// ---------------- main-path workspace layout (bytes) ----------------
// featT2 : [2][HW][512] f32 channel-halved = 67,108,864
// outT   : [NA*NR][1024] f32              = 58,982,400
// plist  : NA x HW u16                    =  3,932,160  (cnts2 aliased at front)
// offs2  : 120 x 961 int                  =    461,280
// tabs   : 2*NA f32
#define WS_FEATT 0UL
#define WS_OUTT  67108864UL
#define WS_PLIST 126091264UL
#define WS_CNTS2 126091264UL            // aliases plist; dead before scatter2 writes
#define WS_OFFS2 130023424UL
#define WS_TABS  130484704UL
#define WS2_NEEDED (130484704UL + 1024UL)

// ---------------- fallback (round-3) workspace layout ----------------
#define F_FEATT 0UL
#define F_OUTT  67108864UL
#define F_PLIST (67108864UL + 58982400UL)
#define F_TABS  (126091264UL + 3932160UL)
#define F_CNTS  (130023424UL + 1024UL)
#define F_OFFS  (130024448UL + 57600UL + 64UL)

// ---- cos/sin tables, fp64 exactly like numpy then cast to f32 ----
__global__ void k_tab(float* __restrict__ tabs) {
    int a = threadIdx.x;
    if (a < NA) {
        double itheta = PI_D / (double)NA;
        double diag   = sqrt((double)(HH * HH + WW * WW));
        double irho   = floor(diag + 1.0) / (double)(NR - 1);   // 182/119
        double ang    = (double)a * itheta;
        tabs[a]       = (float)(cos(ang) / irho);
        tabs[NA + a]  = (float)(sin(ang) / irho);
    }
}

// rho bin — MUST match numpy: f32 mul, f32 mul, f32 add (no fma), rint, clip.
__device__ __forceinline__ int rho_bin(int p, float tc, float ts) {
#pragma clang fp contract(off)
    int y = p >> 7, x = p & (WW - 1);
    float u = (float)(x - WW / 2) * tc;
    float v = (float)(y - HH / 2) * ts;
    float s = u + v;
    int r = (int)rintf(s) + NR / 2;
    return min(NR - 1, max(0, r));
}

// slab id of pixel p: g = y >> 4 = p >> 11   (16-row slabs)
__device__ __forceinline__ int key2(int p, float tc, float ts) {
    return (p >> 11) * NR + rho_bin(p, tc, ts);
}

// ---- register-accumulate over one CSR segment (8-deep MLP); stride in f4 ----
__device__ __forceinline__ float4 accum_bin(const float4* __restrict__ f4,
                                            const unsigned short* __restrict__ pl,
                                            int k0, int k1, int t, int stride) {
    float4 a0 = {0.f, 0.f, 0.f, 0.f}, a1 = a0, a2 = a0, a3 = a0;
    int k = k0;
    for (; k + 8 <= k1; k += 8) {
        int p0 = pl[k + 0], p1 = pl[k + 1], p2 = pl[k + 2], p3 = pl[k + 3];
        int p4 = pl[k + 4], p5 = pl[k + 5], p6 = pl[k + 6], p7 = pl[k + 7];
        float4 v0 = f4[(size_t)p0 * stride + t];
        float4 v1 = f4[(size_t)p1 * stride + t];
        float4 v2 = f4[(size_t)p2 * stride + t];
        float4 v3 = f4[(size_t)p3 * stride + t];
        float4 v4 = f4[(size_t)p4 * stride + t];
        float4 v5 = f4[(size_t)p5 * stride + t];
        float4 v6 = f4[(size_t)p6 * stride + t];
        float4 v7 = f4[(size_t)p7 * stride + t];
        a0.x += v0.x; a0.y += v0.y; a0.z += v0.z; a0.w += v0.w;
        a1.x += v1.x; a1.y += v1.y; a1.z += v1.z; a1.w += v1.w;
        a2.x += v2.x; a2.y += v2.y; a2.z += v2.z; a2.w += v2.w;
        a3.x += v3.x; a3.y += v3.y; a3.z += v3.z; a3.w += v3.w;
        a0.x += v4.x; a0.y += v4.y; a0.z += v4.z; a0.w += v4.w;
        a1.x += v5.x; a1.y += v5.y; a1.z += v5.z; a1.w += v5.w;
        a2.x += v6.x; a2.y += v6.y; a2.z += v6.z; a2.w += v6.w;
        a3.x += v7.x; a3.y += v7.y; a3.z += v7.z; a3.w += v7.w;
    }
    for (; k + 4 <= k1; k += 4) {
        int p0 = pl[k + 0], p1 = pl[k + 1], p2 = pl[k + 2], p3 = pl[k + 3];
        float4 v0 = f4[(size_t)p0 * stride + t];
        float4 v1 = f4[(size_t)p1 * stride + t];
        float4 v2 = f4[(size_t)p2 * stride + t];
        float4 v3 = f4[(size_t)p3 * stride + t];
        a0.x += v0.x; a0.y += v0.y; a0.z += v0.z; a0.w += v0.w;
        a1.x += v1.x; a1.y += v1.y; a1.z += v1.z; a1.w += v1.w;
        a2.x += v2.x; a2.y += v2.y; a2.z += v2.z; a2.w += v2.w;
        a3.x += v3.x; a3.y += v3.y; a3.z += v3.z; a3.w += v3.w;
    }
    for (; k < k1; ++k) {
        float4 v = f4[(size_t)pl[k] * stride + t];
        a0.x += v.x; a0.y += v.y; a0.z += v.z; a0.w += v.w;
    }
    float4 s;
    s.x = (a0.x + a1.x) + (a2.x + a3.x);
    s.y = (a0.y + a1.y) + (a2.y + a3.y);
    s.z = (a0.z + a1.z) + (a2.z + a3.z);
    s.w = (a0.w + a1.w) + (a2.w + a3.w);
    return s;
}

// =================== main path ===================

__global__ __launch_bounds__(256) void k_count2(const float* __restrict__ tabs,
                                                int* __restrict__ cnts2) {
    __shared__ int cnt[NB2];
    int a = blockIdx.x, t = threadIdx.x;
    for (int i = t; i < NB2; i += 256) cnt[i] = 0;
    __syncthreads();
    float tc = tabs[a], ts = tabs[NA + a];
    for (int p = t; p < HW; p += 256)
        atomicAdd(&cnt[key2(p, tc, ts)], 1);
    __syncthreads();
    for (int i = t; i < NB2; i += 256) cnts2[a * NB2 + i] = cnt[i];
}

__global__ void k_scan2(const int* __restrict__ cnts2, int* __restrict__ offs2) {
    int a = threadIdx.x;
    if (a < NA) {
        int base = 0;
        for (int b = 0; b < NB2; ++b) {
            offs2[a * (NB2 + 1) + b] = base;
            base += cnts2[a * NB2 + b];
        }
        offs2[a * (NB2 + 1) + NB2] = base;   // == HW
    }
}

__global__ __launch_bounds__(256) void k_scatter2(const float* __restrict__ tabs,
                                                  const int* __restrict__ offs2,
                                                  unsigned short* __restrict__ plist) {
    __shared__ int cur[NB2];
    int a = blockIdx.x, t = threadIdx.x;
    for (int i = t; i < NB2; i += 256) cur[i] = offs2[a * (NB2 + 1) + i];
    __syncthreads();
    float tc = tabs[a], ts = tabs[NA + a];
    for (int p = t; p < HW; p += 256) {
        int pos = atomicAdd(&cur[key2(p, tc, ts)], 1);
        plist[(size_t)a * HW + pos] = (unsigned short)p;
    }
}

// transpose feat (NC x HW) -> featT2 [h][p][512] channel-halved
__global__ __launch_bounds__(256) void k_tr_in2(const float* __restrict__ in,
                                                float* __restrict__ outp) {
    __shared__ float tile[32][33];
    int p0 = blockIdx.x * 32, c0 = blockIdx.y * 32;
    int tx = threadIdx.x, ty = threadIdx.y;
    for (int i = 0; i < 32; i += 8)
        tile[ty + i][tx] = in[(size_t)(c0 + ty + i) * HW + p0 + tx];
    __syncthreads();
    int c = c0 + tx;                       // channel after transpose
    size_t hbase = (size_t)(c >> 9) * ((size_t)HW * 512) + (c & 511);
    for (int i = 0; i < 32; i += 8)
        outp[hbase + (size_t)(p0 + ty + i) * 512] = tile[tx][ty + i];
}

// zero outT (3,686,400 float4)
__global__ __launch_bounds__(256) void k_zero(float4* __restrict__ o) {
    o[(size_t)blockIdx.x * 256 + threadIdx.x] = make_float4(0.f, 0.f, 0.f, 0.f);
}

// Main gather: block = (slab g, angle a, z = h*2 + parity). Linear id
// = g + 8*(a + 120*z) -> XCD = g; z slowest -> during phase h all 120
// angle-blocks of slab g's 4MB channel-half co-reside on XCD g -> L2 hits.
// Partial (a,g,r) sums merged into outT via device-scope f32 atomics.
__global__ __launch_bounds__(128) void k_gather2(const float4* __restrict__ featT4,
        const int* __restrict__ offs2, const unsigned short* __restrict__ plist,
        float* __restrict__ outT) {
    const int g = blockIdx.x, a = blockIdx.y, z = blockIdx.z;
    const int h = z >> 1, s = z & 1;
    const int t = threadIdx.x;             // 128 thr x float4 = 512 ch (one half)
    const unsigned short* pl = plist + (size_t)a * HW;
    const int* po = offs2 + a * (NB2 + 1) + g * NR;
    const float4* f4 = featT4 + (size_t)h * HW * 128;     // half base, stride 128 f4
    float* ob = outT + (size_t)a * NR * 1024 + h * 512 + t * 4;
    for (int r = s; r < NR; r += 2) {
        int k0 = po[r], k1 = po[r + 1];
        if (k0 == k1) continue;
        float4 v = accum_bin(f4, pl, k0, k1, t, 128);
        float* o = ob + (size_t)r * 1024;
        atomicAdd(o + 0, v.x);
        atomicAdd(o + 1, v.y);
        atomicAdd(o + 2, v.z);
        atomicAdd(o + 3, v.w);
    }
}

// transpose outT ((NA*NR) x NC) -> out (NC x (NA*NR))
__global__ __launch_bounds__(256) void k_tr_out(const float* __restrict__ in,
                                                float* __restrict__ outp) {
    __shared__ float tile[32][33];
    int j0 = blockIdx.x * 32, c0 = blockIdx.y * 32;
    int tx = threadIdx.x, ty = threadIdx.y;
    for (int i = 0; i < 32; i += 8)
        tile[ty + i][tx] = in[(size_t)(j0 + ty + i) * NC + c0 + tx];
    __syncthreads();
    for (int i = 0; i < 32; i += 8)
        outp[(size_t)(c0 + ty + i) * (NA * NR) + j0 + tx] = tile[tx][ty + i];
}

// =================== fallback path (round-3, known-good) ===================

__global__ __launch_bounds__(256) void k_count(const float* __restrict__ tabs,
                                               int* __restrict__ cnts) {
    __shared__ int cnt[NR];
    int a = blockIdx.x, t = threadIdx.x;
    if (t < NR) cnt[t] = 0;
    __syncthreads();
    float tc = tabs[a], ts = tabs[NA + a];
    for (int p = t; p < HW; p += 256)
        atomicAdd(&cnt[rho_bin(p, tc, ts)], 1);
    __syncthreads();
    if (t < NR) cnts[a * NR + t] = cnt[t];
}

__global__ void k_scan(const int* __restrict__ cnts, int* __restrict__ offs) {
    int a = threadIdx.x;
    if (a < NA) {
        int base = 0;
        for (int r = 0; r < NR; ++r) {
            offs[a * (NR + 1) + r] = base;
            base += cnts[a * NR + r];
        }
        offs[a * (NR + 1) + NR] = base;
    }
}

__global__ __launch_bounds__(256) void k_scatter(const float* __restrict__ tabs,
                                                 const int* __restrict__ offs,
                                                 unsigned short* __restrict__ plist) {
    __shared__ int cur[NR];
    int a = blockIdx.x, t = threadIdx.x;
    if (t < NR) cur[t] = offs[a * (NR + 1) + t];
    __syncthreads();
    float tc = tabs[a], ts = tabs[NA + a];
    for (int p = t; p < HW; p += 256) {
        int r = rho_bin(p, tc, ts);
        int pos = atomicAdd(&cur[r], 1);
        plist[(size_t)a * HW + pos] = (unsigned short)p;
    }
}

__global__ __launch_bounds__(256) void k_tr_in(const float* __restrict__ in,
                                               float* __restrict__ outp) {
    __shared__ float tile[32][33];
    int p0 = blockIdx.x * 32, c0 = blockIdx.y * 32;
    int tx = threadIdx.x, ty = threadIdx.y;
    for (int i = 0; i < 32; i += 8)
        tile[ty + i][tx] = in[(size_t)(c0 + ty + i) * HW + p0 + tx];
    __syncthreads();
    for (int i = 0; i < 32; i += 8)
        outp[(size_t)(p0 + ty + i) * NC + c0 + tx] = tile[tx][ty + i];
}

__global__ __launch_bounds__(256) void k_gather(const float4* __restrict__ featT4,
                                                const int* __restrict__ offs,
                                                const unsigned short* __restrict__ plist,
                                                float4* __restrict__ outT4) {
    const int r = blockIdx.x, a = blockIdx.y, t = threadIdx.x;
    const unsigned short* pl = plist + (size_t)a * HW;
    int k0 = offs[a * (NR + 1) + r];
    int k1 = offs[a * (NR + 1) + r + 1];
    float4 s = accum_bin(featT4, pl, k0, k1, t, 256);
    outT4[(size_t)(a * NR + r) * 256 + t] = s;
}

// =================== launch ===================

extern "C" void kernel_launch(void* const* d_in, const int* in_sizes, int n_in,
                              void* d_out, int out_size, void* d_ws, size_t ws_size,
                              hipStream_t stream) {
    (void)in_sizes; (void)n_in; (void)out_size;
    const float* feat = (const float*)d_in[0];
    float* out = (float*)d_out;
    char* ws = (char*)d_ws;

    if (ws_size >= WS2_NEEDED) {
        // ---------------- main path ----------------
        float*          featT = (float*)(ws + WS_FEATT);
        float*          outT  = (float*)(ws + WS_OUTT);
        unsigned short* plist = (unsigned short*)(ws + WS_PLIST);
        int*            cnts2 = (int*)(ws + WS_CNTS2);   // aliases plist (dead before scatter2)
        int*            offs2 = (int*)(ws + WS_OFFS2);
        float*          tabs  = (float*)(ws + WS_TABS);

        k_tab     <<<1, 128, 0, stream>>>(tabs);
        k_count2  <<<NA, 256, 0, stream>>>(tabs, cnts2);
        k_scan2   <<<1, 128, 0, stream>>>(cnts2, offs2);
        k_scatter2<<<NA, 256, 0, stream>>>(tabs, offs2, plist);
        k_tr_in2  <<<dim3(HW / 32, NC / 32), dim3(32, 8), 0, stream>>>(feat, featT);
        k_zero    <<<(NA * NR * NC / 4) / 256, 256, 0, stream>>>((float4*)outT);
        k_gather2 <<<dim3(G, NA, 4), 128, 0, stream>>>(
            (const float4*)featT, offs2, plist, outT);
        k_tr_out  <<<dim3((NA * NR) / 32, NC / 32), dim3(32, 8), 0, stream>>>(outT, out);
    } else {
        // ---------------- fallback: round-3 path ----------------
        float*          featT = (float*)(ws + F_FEATT);
        float*          outT  = (float*)(ws + F_OUTT);
        unsigned short* plist = (unsigned short*)(ws + F_PLIST);
        float*          tabs  = (float*)(ws + F_TABS);
        int*            cnts  = (int*)(ws + F_CNTS);
        int*            offs  = (int*)(ws + F_OFFS);

        k_tab    <<<1, 128, 0, stream>>>(tabs);
        k_count  <<<NA, 256, 0, stream>>>(tabs, cnts);
        k_scan   <<<1, 128, 0, stream>>>(cnts, offs);
        k_scatter<<<NA, 256, 0, stream>>>(tabs, offs, plist);
        k_tr_in  <<<dim3(HW / 32, NC / 32), dim3(32, 8), 0, stream>>>(feat, featT);
        k_gather <<<dim3(NR, NA), 256, 0, stream>>>(
            (const float4*)featT, offs, plist, (float4*)outT);
        k_tr_out <<<dim3((NA * NR) / 32, NC / 32), dim3(32, 8), 0, stream>>>(outT, out);
    }
}